// Round 10
// baseline (194.489 us; speedup 1.0000x reference)
//
#include <hip/hip_runtime.h>
#include <hip/hip_bf16.h>
#include <hip/hip_fp8.h>
#include <stdint.h>

#define P_B 4096
#define P_N 16384
#define P_F 768
#define P_E 512
#define NKT_F 24   // 768/32 k-tiles (bf16 packing, embed operands)
#define NKTP_E 8   // 512/64 k-tile-pairs (fp8 packing, echo operands)
#define CPAD 776   // convert LDS row pad (bf16 elems)
#define EPAD 136   // embed epilogue LDS row pad (bf16 elems)

typedef __attribute__((ext_vector_type(8))) __bf16 bf16x8;
typedef __attribute__((ext_vector_type(4))) float f32x4;

__device__ __forceinline__ unsigned short bfbits(float x) {
    __bf16 h = (__bf16)x;
    union { __bf16 h; unsigned short u; } cv;
    cv.h = h;
    return cv.u;
}
__device__ __forceinline__ float bf2f(unsigned short u) {
    union { float f; unsigned int i; } cv;
    cv.i = ((unsigned int)u) << 16;
    return cv.f;
}
__device__ __forceinline__ unsigned char f8bits(float x) {
    __hip_fp8_e4m3 h(x);           // OCP e4m3 on gfx950
    return (unsigned char)h.__x;
}

// bf16 fragment-packed (embed operands): element (r,k) ->
//   (((r>>4)*NKT_F + (k>>5))*64 + ((k>>3)&3)*16 + (r&15))*8 + (k&7)
// fp8 fragment-packed (echo operands), K grouped by 64 (two K=32 MFMA frags
// per 16B lane chunk): element (r,k) -> byte
//   (((r>>4)*NKTP_E + (k>>6))*64 + (((k>>3)&3)*16 + (r&15)))*16
//     + ((k>>5)&1)*8 + (k&7)

// ---------------------------------------------------------------------------
// Convert+pack (+ zero-init of norm2/echo): fp32 row-major -> bf16
// fragment-packed via LDS transpose. Blocks 0..255 = X, 256..1279 = D,
// 1280..1311 = gw.  (r6-proven)
// ---------------------------------------------------------------------------
__global__ __launch_bounds__(256) void convert_pack_kernel(
    const float* __restrict__ X, const float* __restrict__ D,
    const float* __restrict__ gw,
    unsigned short* __restrict__ xdpk, unsigned short* __restrict__ gwpk,
    float* __restrict__ zbase)   // norm2(20480) | echo(4096)
{
    __shared__ unsigned short T[16 * CPAD];
    const int tid = threadIdx.x;
    const int rb = blockIdx.x;          // 0..1311

    if (rb < 97) {
        const int z = rb * 256 + tid;
        if (z < P_B + P_N + P_B) zbase[z] = 0.0f;
    }

    const float* src;
    unsigned short* dstbase;
    if (rb < 256)       { src = X  + (size_t)rb * 16 * P_F;          dstbase = xdpk + (size_t)rb * NKT_F * 512; }
    else if (rb < 1280) { src = D  + (size_t)(rb - 256) * 16 * P_F;  dstbase = xdpk + (size_t)rb * NKT_F * 512; }
    else                { src = gw + (size_t)(rb - 1280) * 16 * P_F; dstbase = gwpk + (size_t)(rb - 1280) * NKT_F * 512; }

#pragma unroll
    for (int it = 0; it < 12; ++it) {
        const int flat = it * 1024 + tid * 4;
        const int row = flat / P_F;
        const int col = flat - row * P_F;
        const float4 v = *(const float4*)(src + (size_t)row * P_F + col);
        unsigned short* t = &T[row * CPAD + col];
        t[0] = bfbits(v.x); t[1] = bfbits(v.y); t[2] = bfbits(v.z); t[3] = bfbits(v.w);
    }
    __syncthreads();

#pragma unroll
    for (int it = 0; it < 6; ++it) {
        const int m = it * 256 + tid;
        const int kt = m >> 6;          // 0..23
        const int lane = m & 63;
        const int r = lane & 15;
        const int k = kt * 32 + (lane >> 4) * 8;
        const uint4 frag = *(const uint4*)(&T[r * CPAD + k]);
        *(uint4*)(dstbase + (size_t)(kt * 64 + lane) * 8) = frag;
    }
}

// ---------------------------------------------------------------------------
// Embed (r9-verified: XCD-affinity remap + setprio): emb = xd·gw^T + gb,
// barrier-free bf16 K-loop, 4-wave 128x128 blocks.  Remap puts all 4
// colTiles of a rowTile on one XCD (A-panel L2 dedup, -4 us r8->r9).
// DO NOT TOUCH — byte-identical to r9.
// ---------------------------------------------------------------------------
__global__ __launch_bounds__(256, 2) void embed_pk_kernel(
    const unsigned short* __restrict__ xdpk, const unsigned short* __restrict__ gwpk,
    const float* __restrict__ gb,
    unsigned char* __restrict__ embpk8, float* __restrict__ norm2)
{
    __shared__ unsigned short Es[128 * EPAD];
    const int tid = threadIdx.x, lane = tid & 63, wave = tid >> 6;
    const int q = lane >> 4, c = lane & 15;
    const int flat = blockIdx.x + 4 * blockIdx.y;
    const int xcd = flat & 7;
    const int idx = flat >> 3;            // 0..79
    const int rowTile = xcd * 20 + (idx >> 2);   // 0..159
    const int colTile = idx & 3;                 // 0..3
    const int rbA0 = rowTile * 8 + (wave >> 1) * 4;
    const int rbB0 = colTile * 8 + (wave & 1) * 4;

    const unsigned short* pa[4];
    const unsigned short* pb[4];
#pragma unroll
    for (int i = 0; i < 4; i++)
        pa[i] = xdpk + ((size_t)(rbA0 + i) * NKT_F * 64 + lane) * 8;
#pragma unroll
    for (int j = 0; j < 4; j++)
        pb[j] = gwpk + ((size_t)(rbB0 + j) * NKT_F * 64 + lane) * 8;

    f32x4 acc[4][4];
    const f32x4 zero = {0.f, 0.f, 0.f, 0.f};
#pragma unroll
    for (int i = 0; i < 4; i++)
#pragma unroll
        for (int j = 0; j < 4; j++) acc[i][j] = zero;

#pragma unroll
    for (int kt = 0; kt < NKT_F; ++kt) {
        bf16x8 af[4], bfr[4];
#pragma unroll
        for (int i = 0; i < 4; i++) af[i] = *(const bf16x8*)(pa[i] + (size_t)kt * 512);
#pragma unroll
        for (int j = 0; j < 4; j++) bfr[j] = *(const bf16x8*)(pb[j] + (size_t)kt * 512);
        __builtin_amdgcn_s_setprio(1);
#pragma unroll
        for (int i = 0; i < 4; i++)
#pragma unroll
            for (int j = 0; j < 4; j++)
                acc[i][j] = __builtin_amdgcn_mfma_f32_16x16x32_bf16(af[i], bfr[j], acc[i][j], 0, 0, 0);
        __builtin_amdgcn_s_setprio(0);
    }

    // epilogue: bias, ssq (bf16 values), bf16 LDS stash
    float ss[4][4];
#pragma unroll
    for (int i = 0; i < 4; i++)
#pragma unroll
        for (int r = 0; r < 4; r++) ss[i][r] = 0.f;
#pragma unroll
    for (int j = 0; j < 4; j++) {
        const int lcbase = (wave & 1) * 64 + j * 16 + c;
        const float bias = gb[colTile * 128 + lcbase];
#pragma unroll
        for (int i = 0; i < 4; i++) {
#pragma unroll
            for (int r = 0; r < 4; r++) {
                const int lr = (wave >> 1) * 64 + i * 16 + q * 4 + r;
                const float v = acc[i][j][r] + bias;
                const unsigned short hb = bfbits(v);
                Es[lr * EPAD + lcbase] = hb;
                const float vs = bf2f(hb);
                ss[i][r] = fmaf(vs, vs, ss[i][r]);
            }
        }
    }
#pragma unroll
    for (int i = 0; i < 4; i++)
#pragma unroll
        for (int r = 0; r < 4; r++) {
            float s = ss[i][r];
            s += __shfl_xor(s, 1);
            s += __shfl_xor(s, 2);
            s += __shfl_xor(s, 4);
            s += __shfl_xor(s, 8);
            ss[i][r] = s;
        }
    if (c == 0) {
#pragma unroll
        for (int i = 0; i < 4; i++)
#pragma unroll
            for (int r = 0; r < 4; r++) {
                const int rowg = rowTile * 128 + (wave >> 1) * 64 + i * 16 + q * 4 + r;
                atomicAdd(&norm2[rowg], ss[i][r]);
            }
    }
    __syncthreads();

    // fp8 packed store: 8 rbl x 2 ktp x 64 lanes x 16B = 1024 chunks, 4 iters.
#pragma unroll
    for (int it = 0; it < 4; ++it) {
        const int m = it * 256 + tid;
        const int rbl = m >> 7;             // 0..7
        const int rest = m & 127;
        const int ktpl = rest >> 6;         // 0..1
        const int lane2 = rest & 63;
        const int r2 = lane2 & 15;
        const int q2 = lane2 >> 4;
        const int lr = rbl * 16 + r2;
        const unsigned short* e0 = &Es[lr * EPAD + ktpl * 64 + q2 * 8];
        const unsigned short* e1 = e0 + 32;
        union { unsigned char b[16]; uint4 v; } outw;
#pragma unroll
        for (int t = 0; t < 8; t++) outw.b[t]     = f8bits(bf2f(e0[t]));
#pragma unroll
        for (int t = 0; t < 8; t++) outw.b[8 + t] = f8bits(bf2f(e1[t]));
        const size_t rb = (size_t)(rowTile * 8 + rbl);
        const size_t ktp = (size_t)(colTile * 2 + ktpl);
        *(uint4*)(embpk8 + ((rb * NKTP_E + ktp) * 64 + lane2) * 16) = outw.v;
    }
}

// ---------------------------------------------------------------------------
// Echo (fp8, r7-locked macro-structure + NEW 2-stage register double-buffer
// + folded finalize).  Evidence for the prefetch: r7-r9 show VGPR=60 — the
// compiler allocates NO prefetch regs, so each ktp is load->wait->MFMA
// serial; MfmaUtil 45% ~ MFMA(33us)+exposed loads(27us) = 60us sum-like.
// Explicit ping-pong (a0/b0, a1/b1) hides each iteration's loads under the
// previous iteration's 32-MFMA cluster.  Barrier-free, so the m131-141
// "source pipelining is futile" lesson (vmcnt0+barrier drain) doesn't apply.
// ~150 total regs -> 3 waves/SIMD (traded 4th wave for in-wave ILP).
// Folded finalize: inv_norm^3 (X) and inv_norm^3*(2r-1) (D) computed on the
// fly from raw norm2 — identical arithmetic, one fewer dispatch.
// ---------------------------------------------------------------------------
__global__ __launch_bounds__(256, 2) void echo_pk_kernel(
    const unsigned char* __restrict__ embpk8, const float* __restrict__ norm2,
    const float* __restrict__ rr, float* __restrict__ echo)
{
    const int tid = threadIdx.x, lane = tid & 63, wave = tid >> 6;
    const int q = lane >> 4, c = lane & 15;
    const int bid = blockIdx.x;          // 0..4095
    const int sb = bid >> 6, w = bid & 63;
    const int btile = (sb & 3) * 8 + (w & 7);    // 0..31
    const int ntile = (sb >> 2) * 8 + (w >> 3);  // 0..127
    const int row0 = btile * 128;
    const int col0 = ntile * 128;
    const int rbA0 = btile * 8 + (wave >> 1) * 4;
    const int rbB0 = 256 + ntile * 8 + (wave & 1) * 4;   // De rows start at rb 256

    const unsigned char* pa[4];
    const unsigned char* pb[4];
#pragma unroll
    for (int i = 0; i < 4; i++)
        pa[i] = embpk8 + ((size_t)(rbA0 + i) * NKTP_E * 64 + lane) * 16;
#pragma unroll
    for (int j = 0; j < 4; j++)
        pb[j] = embpk8 + ((size_t)(rbB0 + j) * NKTP_E * 64 + lane) * 16;

    f32x4 acc[4][4];
    const f32x4 zero = {0.f, 0.f, 0.f, 0.f};
#pragma unroll
    for (int i = 0; i < 4; i++)
#pragma unroll
        for (int j = 0; j < 4; j++) acc[i][j] = zero;

    union bufu { uint4 v; long l[2]; };
    bufu a0[4], b0[4], a1[4], b1[4];

    // prologue: ktp 0 into set 0
#pragma unroll
    for (int i = 0; i < 4; i++) a0[i].v = *(const uint4*)(pa[i]);
#pragma unroll
    for (int j = 0; j < 4; j++) b0[j].v = *(const uint4*)(pb[j]);

#pragma unroll
    for (int ktp = 0; ktp < NKTP_E; ktp += 2) {
        // prefetch ktp+1 into set 1 (always valid: NKTP_E even)
#pragma unroll
        for (int i = 0; i < 4; i++) a1[i].v = *(const uint4*)(pa[i] + (size_t)(ktp + 1) * 1024);
#pragma unroll
        for (int j = 0; j < 4; j++) b1[j].v = *(const uint4*)(pb[j] + (size_t)(ktp + 1) * 1024);
        __builtin_amdgcn_s_setprio(1);
#pragma unroll
        for (int h = 0; h < 2; h++)
#pragma unroll
            for (int i = 0; i < 4; i++)
#pragma unroll
                for (int j = 0; j < 4; j++)
                    acc[i][j] = __builtin_amdgcn_mfma_f32_16x16x32_fp8_fp8(
                        a0[i].l[h], b0[j].l[h], acc[i][j], 0, 0, 0);
        __builtin_amdgcn_s_setprio(0);
        // prefetch ktp+2 into set 0
        if (ktp + 2 < NKTP_E) {
#pragma unroll
            for (int i = 0; i < 4; i++) a0[i].v = *(const uint4*)(pa[i] + (size_t)(ktp + 2) * 1024);
#pragma unroll
            for (int j = 0; j < 4; j++) b0[j].v = *(const uint4*)(pb[j] + (size_t)(ktp + 2) * 1024);
        }
        __builtin_amdgcn_s_setprio(1);
#pragma unroll
        for (int h = 0; h < 2; h++)
#pragma unroll
            for (int i = 0; i < 4; i++)
#pragma unroll
                for (int j = 0; j < 4; j++)
                    acc[i][j] = __builtin_amdgcn_mfma_f32_16x16x32_fp8_fp8(
                        a1[i].l[h], b1[j].l[h], acc[i][j], 0, 0, 0);
        __builtin_amdgcn_s_setprio(0);
    }

    // epilogue: cube, weight by inv_normD^3*(2r-1), reduce over columns,
    // scale rows by inv_normX^3, atomicAdd.  (finalize folded in — same math)
    float wc[4];
#pragma unroll
    for (int j = 0; j < 4; j++) {
        const int cd = col0 + (wave & 1) * 64 + j * 16 + c;
        const float nD = norm2[P_B + cd];
        const float nrmD = fmaxf(sqrtf(nD), 1e-12f);
        const float invD = 1.0f / nrmD;
        wc[j] = invD * invD * invD * (2.0f * rr[cd] - 1.0f);
    }
    float p[4][4];
#pragma unroll
    for (int i = 0; i < 4; i++)
#pragma unroll
        for (int r = 0; r < 4; r++) p[i][r] = 0.f;
#pragma unroll
    for (int i = 0; i < 4; i++)
#pragma unroll
        for (int j = 0; j < 4; j++)
#pragma unroll
            for (int r = 0; r < 4; r++) {
                const float v = acc[i][j][r];
                const float v3 = v * v * v;
                p[i][r] = fmaf(v3, wc[j], p[i][r]);
            }
#pragma unroll
    for (int i = 0; i < 4; i++)
#pragma unroll
        for (int r = 0; r < 4; r++) {
            float s = p[i][r];
            s += __shfl_xor(s, 1);
            s += __shfl_xor(s, 2);
            s += __shfl_xor(s, 4);
            s += __shfl_xor(s, 8);
            p[i][r] = s;
        }
    if (c == 0) {
#pragma unroll
        for (int i = 0; i < 4; i++)
#pragma unroll
            for (int r = 0; r < 4; r++) {
                const int rowg = row0 + (wave >> 1) * 64 + i * 16 + q * 4 + r;
                const float nX = norm2[rowg];
                const float nrmX = fmaxf(sqrtf(nX), 1e-12f);
                const float invX = 1.0f / nrmX;
                atomicAdd(&echo[rowg], p[i][r] * (invX * invX * invX));
            }
    }
}

// ---------------------------------------------------------------------------
// Head: logits = echo*h_w + h_b ; preds = sigmoid(logits)
// ---------------------------------------------------------------------------
__global__ void head_kernel(const float* __restrict__ echo, const float* __restrict__ hw,
                            const float* __restrict__ hb, float* __restrict__ out)
{
    const int i = blockIdx.x * 256 + threadIdx.x;
    if (i >= P_B) return;
    const float logit = fmaf(echo[i], hw[0], hb[0]);
    out[i] = logit;
    out[P_B + i] = 1.0f / (1.0f + expf(-logit));
}

extern "C" void kernel_launch(void* const* d_in, const int* in_sizes, int n_in,
                              void* d_out, int out_size, void* d_ws, size_t ws_size,
                              hipStream_t stream)
{
    const float* X  = (const float*)d_in[0];
    const float* D  = (const float*)d_in[1];
    const float* r  = (const float*)d_in[2];
    const float* gw = (const float*)d_in[3];
    const float* gb = (const float*)d_in[4];
    const float* hw = (const float*)d_in[5];
    const float* hb = (const float*)d_in[6];
    float* out = (float*)d_out;

    char* ws = (char*)d_ws;
    const size_t xdpk_bytes   = (size_t)1280 * NKT_F * 64 * 8 * 2;    // 31,457,280
    const size_t gwpk_bytes   = (size_t)32 * NKT_F * 64 * 8 * 2;      //    786,432
    const size_t embpk8_bytes = (size_t)1280 * NKTP_E * 64 * 16;      // 10,485,760

    unsigned short* xdpk   = (unsigned short*)ws;
    unsigned short* gwpk   = (unsigned short*)(ws + xdpk_bytes);
    unsigned char*  embpk8 = (unsigned char*)(ws + xdpk_bytes + gwpk_bytes);
    float* norm2 = (float*)(ws + xdpk_bytes + gwpk_bytes + embpk8_bytes);
    float* echo = norm2 + (P_B + P_N);

    convert_pack_kernel<<<dim3(1312), 256, 0, stream>>>(X, D, gw, xdpk, gwpk, norm2);
    embed_pk_kernel<<<dim3(4, 160), 256, 0, stream>>>(xdpk, gwpk, gb, embpk8, norm2);
    echo_pk_kernel<<<dim3(4096), 256, 0, stream>>>(embpk8, norm2, r, echo);
    head_kernel<<<dim3((P_B + 255) / 256), 256, 0, stream>>>(echo, hw, hb, out);
}

// Round 11
// 181.649 us; speedup vs baseline: 1.0707x; 1.0707x over previous
//
#include <hip/hip_runtime.h>
#include <hip/hip_bf16.h>
#include <hip/hip_fp8.h>
#include <stdint.h>

#define P_B 4096
#define P_N 16384
#define P_F 768
#define P_E 512
#define NKT_F 24   // 768/32 k-tiles (bf16 packing, embed operands)
#define NKTP_E 8   // 512/64 k-tile-pairs (fp8 packing, echo operands)
#define CPAD 776   // stage LDS row pad (bf16 elems)
#define EPAD3 520  // fused-embed epilogue LDS row pad (bf16 elems)

typedef __attribute__((ext_vector_type(8))) __bf16 bf16x8;
typedef __attribute__((ext_vector_type(4))) float f32x4;

__device__ __forceinline__ unsigned short bfbits(float x) {
    __bf16 h = (__bf16)x;
    union { __bf16 h; unsigned short u; } cv;
    cv.h = h;
    return cv.u;
}
__device__ __forceinline__ float bf2f(unsigned short u) {
    union { float f; unsigned int i; } cv;
    cv.i = ((unsigned int)u) << 16;
    return cv.f;
}
__device__ __forceinline__ unsigned char f8bits(float x) {
    __hip_fp8_e4m3 h(x);           // OCP e4m3 on gfx950
    return (unsigned char)h.__x;
}

// bf16 fragment-packed (gw operand): element (r,k) ->
//   (((r>>4)*NKT_F + (k>>5))*64 + ((k>>3)&3)*16 + (r&15))*8 + (k&7)
// fp8 fragment-packed (echo operands), K grouped by 64: element (r,k) -> byte
//   (((r>>4)*NKTP_E + (k>>6))*64 + (((k>>3)&3)*16 + (r&15)))*16
//     + ((k>>5)&1)*8 + (k&7)

// ---------------------------------------------------------------------------
// gw pack + zero-init of norm2/echo.  Blocks 0..31 pack gw (r6-proven LDS
// transpose); all 97 blocks zero a slice of norm2|echo.  xdpk is GONE —
// X/D conversion is fused into embed (r11).
// ---------------------------------------------------------------------------
__global__ __launch_bounds__(256) void convert_pack_kernel(
    const float* __restrict__ gw, unsigned short* __restrict__ gwpk,
    float* __restrict__ zbase)   // norm2(20480) | echo(4096)
{
    __shared__ unsigned short T[16 * CPAD];
    const int tid = threadIdx.x;
    const int rb = blockIdx.x;          // 0..96

    const int z = rb * 256 + tid;
    if (z < P_B + P_N + P_B) zbase[z] = 0.0f;
    if (rb >= 32) return;

    const float* src = gw + (size_t)rb * 16 * P_F;
    unsigned short* dstbase = gwpk + (size_t)rb * NKT_F * 512;

#pragma unroll
    for (int it = 0; it < 12; ++it) {
        const int flat = it * 1024 + tid * 4;
        const int row = flat / P_F;
        const int col = flat - row * P_F;
        const float4 v = *(const float4*)(src + (size_t)row * P_F + col);
        unsigned short* t = &T[row * CPAD + col];
        t[0] = bfbits(v.x); t[1] = bfbits(v.y); t[2] = bfbits(v.z); t[3] = bfbits(v.w);
    }
    __syncthreads();

#pragma unroll
    for (int it = 0; it < 6; ++it) {
        const int m = it * 256 + tid;
        const int kt = m >> 6;          // 0..23
        const int lane = m & 63;
        const int r = lane & 15;
        const int k = kt * 32 + (lane >> 4) * 8;
        const uint4 frag = *(const uint4*)(&T[r * CPAD + k]);
        *(uint4*)(dstbase + (size_t)(kt * 64 + lane) * 8) = frag;
    }
}

// ---------------------------------------------------------------------------
// Fused convert+embed (r11): each block owns 32 rows x all 512 cols.
// 1) stage: 32x768 fp32 -> bf16 LDS transpose tile (convert's proven
//    load/store patterns).  A is read from HBM ONCE total (63 MB; xdpk's
//    31.5 MB write + re-reads eliminated).
// 2) K-loop: A-fragments via LDS read (convert's proven (r,k) pattern,
//    near-zero latency), B from gwpk (786 KB, L2-resident).  Per wave:
//    2x8 acc (64 AGPR), 16 MFMA/kt — same MFMA count/wave as r9 embed.
// 3) epilogue: bias+ssq+norm2 atomics, bf16 stash, fp8 pack (identical
//    embpk8 bytes as before).
// ---------------------------------------------------------------------------
__global__ __launch_bounds__(256, 2) void embed_pk_kernel(
    const float* __restrict__ X, const float* __restrict__ D,
    const unsigned short* __restrict__ gwpk, const float* __restrict__ gb,
    unsigned char* __restrict__ embpk8, float* __restrict__ norm2)
{
    __shared__ union {
        unsigned short T[32 * CPAD];    // 49.7 KB stage
        unsigned short Es[32 * EPAD3];  // 33.3 KB epilogue stash
    } sh;
    const int tid = threadIdx.x, lane = tid & 63, wave = tid >> 6;
    const int q = lane >> 4, c = lane & 15;
    const int rowTile = blockIdx.x;      // 0..639 (32 rows each)
    const float* src = (rowTile < 128) ? (X + (size_t)rowTile * 32 * P_F)
                                       : (D + (size_t)(rowTile - 128) * 32 * P_F);

    // ---- stage: 32x768 fp32 -> bf16 transpose buffer ----
#pragma unroll
    for (int it = 0; it < 24; ++it) {
        const int flat = it * 1024 + tid * 4;
        const int row = flat / P_F;
        const int col = flat - row * P_F;
        const float4 v = *(const float4*)(src + (size_t)row * P_F + col);
        unsigned short* t = &sh.T[row * CPAD + col];
        t[0] = bfbits(v.x); t[1] = bfbits(v.y); t[2] = bfbits(v.z); t[3] = bfbits(v.w);
    }
    __syncthreads();

    // ---- K-loop: wave w covers cols [w*128, w*128+128) -> cb = w*8+j ----
    const unsigned short* pb[8];
#pragma unroll
    for (int j = 0; j < 8; j++)
        pb[j] = gwpk + ((size_t)(wave * 8 + j) * NKT_F * 64 + lane) * 8;

    f32x4 acc[2][8];
    const f32x4 zero = {0.f, 0.f, 0.f, 0.f};
#pragma unroll
    for (int i = 0; i < 2; i++)
#pragma unroll
        for (int j = 0; j < 8; j++) acc[i][j] = zero;

#pragma unroll
    for (int kt = 0; kt < NKT_F; ++kt) {
        bf16x8 af[2], bfr[8];
#pragma unroll
        for (int i = 0; i < 2; i++)
            af[i] = *(const bf16x8*)(&sh.T[(i * 16 + (lane & 15)) * CPAD
                                           + kt * 32 + (lane >> 4) * 8]);
#pragma unroll
        for (int j = 0; j < 8; j++) bfr[j] = *(const bf16x8*)(pb[j] + (size_t)kt * 512);
        __builtin_amdgcn_s_setprio(1);
#pragma unroll
        for (int i = 0; i < 2; i++)
#pragma unroll
            for (int j = 0; j < 8; j++)
                acc[i][j] = __builtin_amdgcn_mfma_f32_16x16x32_bf16(af[i], bfr[j], acc[i][j], 0, 0, 0);
        __builtin_amdgcn_s_setprio(0);
    }
    __syncthreads();   // done reading T; LDS becomes Es

    // ---- epilogue: bias, ssq (bf16 values), bf16 LDS stash ----
    float ss[2][4];
#pragma unroll
    for (int i = 0; i < 2; i++)
#pragma unroll
        for (int r = 0; r < 4; r++) ss[i][r] = 0.f;
#pragma unroll
    for (int j = 0; j < 8; j++) {
        const int lc = wave * 128 + j * 16 + c;    // 0..511
        const float bias = gb[lc];
#pragma unroll
        for (int i = 0; i < 2; i++) {
#pragma unroll
            for (int r = 0; r < 4; r++) {
                const int lr = i * 16 + q * 4 + r;  // 0..31
                const float v = acc[i][j][r] + bias;
                const unsigned short hb = bfbits(v);
                sh.Es[lr * EPAD3 + lc] = hb;
                const float vs = bf2f(hb);
                ss[i][r] = fmaf(vs, vs, ss[i][r]);
            }
        }
    }
#pragma unroll
    for (int i = 0; i < 2; i++)
#pragma unroll
        for (int r = 0; r < 4; r++) {
            float s = ss[i][r];
            s += __shfl_xor(s, 1);
            s += __shfl_xor(s, 2);
            s += __shfl_xor(s, 4);
            s += __shfl_xor(s, 8);
            ss[i][r] = s;
        }
    if (c == 0) {
#pragma unroll
        for (int i = 0; i < 2; i++)
#pragma unroll
            for (int r = 0; r < 4; r++) {
                const int rowg = rowTile * 32 + i * 16 + q * 4 + r;
                atomicAdd(&norm2[rowg], ss[i][r]);
            }
    }
    __syncthreads();

    // ---- fp8 packed store: 2 rbl x 8 ktp x 64 lanes x 16B, 4 iters ----
#pragma unroll
    for (int it = 0; it < 4; ++it) {
        const int m = it * 256 + tid;       // 0..1023
        const int rbl = m >> 9;             // 0..1
        const int rest = m & 511;
        const int ktpl = rest >> 6;         // 0..7
        const int lane2 = rest & 63;
        const int r2 = lane2 & 15;
        const int q2 = lane2 >> 4;
        const int lr = rbl * 16 + r2;
        const unsigned short* e0 = &sh.Es[lr * EPAD3 + ktpl * 64 + q2 * 8];
        const unsigned short* e1 = e0 + 32;
        union { unsigned char b[16]; uint4 v; } outw;
#pragma unroll
        for (int t = 0; t < 8; t++) outw.b[t]     = f8bits(bf2f(e0[t]));
#pragma unroll
        for (int t = 0; t < 8; t++) outw.b[8 + t] = f8bits(bf2f(e1[t]));
        const size_t rb = (size_t)(rowTile * 2 + rbl);
        *(uint4*)(embpk8 + ((rb * NKTP_E + (size_t)ktpl) * 64 + lane2) * 16) = outw.v;
    }
}

// ---------------------------------------------------------------------------
// Finalize: norm2[i] -> inv_norm^3 (X rows), inv_norm^3 * (2r-1) (D rows)
// ---------------------------------------------------------------------------
__global__ void finalize_kernel(float* __restrict__ nf, const float* __restrict__ r)
{
    const int i = blockIdx.x * 256 + threadIdx.x;
    if (i >= P_B + P_N) return;
    float nrm = sqrtf(nf[i]);
    nrm = fmaxf(nrm, 1e-12f);
    const float inv = 1.0f / nrm;
    float w = inv * inv * inv;
    if (i >= P_B) {
        const float rv = r[i - P_B];
        w *= (2.0f * rv - 1.0f);
    }
    nf[i] = w;
}

// ---------------------------------------------------------------------------
// Echo (fp8, r8-verified byte-identical: 59-60 us, MfmaUtil 46%, VGPR 60 ->
// 124 unified regs -> 4 waves/SIMD, no spill).  Supertile mapping +
// barrier-free fragment K-loop; s_setprio(1) around the MFMA cluster.
// DO NOT TOUCH.  (r10's explicit reg-dbuf regressed: VALUBusy 52%, +6 us.)
// ---------------------------------------------------------------------------
__global__ __launch_bounds__(256, 2) void echo_pk_kernel(
    const unsigned char* __restrict__ embpk8, const float* __restrict__ fbuf,
    float* __restrict__ echo)
{
    const int tid = threadIdx.x, lane = tid & 63, wave = tid >> 6;
    const int q = lane >> 4, c = lane & 15;
    const int bid = blockIdx.x;          // 0..4095
    const int sb = bid >> 6, w = bid & 63;
    const int btile = (sb & 3) * 8 + (w & 7);    // 0..31
    const int ntile = (sb >> 2) * 8 + (w >> 3);  // 0..127
    const int row0 = btile * 128;
    const int col0 = ntile * 128;
    const int rbA0 = btile * 8 + (wave >> 1) * 4;
    const int rbB0 = 256 + ntile * 8 + (wave & 1) * 4;   // De rows start at rb 256

    const unsigned char* pa[4];
    const unsigned char* pb[4];
#pragma unroll
    for (int i = 0; i < 4; i++)
        pa[i] = embpk8 + ((size_t)(rbA0 + i) * NKTP_E * 64 + lane) * 16;
#pragma unroll
    for (int j = 0; j < 4; j++)
        pb[j] = embpk8 + ((size_t)(rbB0 + j) * NKTP_E * 64 + lane) * 16;

    f32x4 acc[4][4];
    const f32x4 zero = {0.f, 0.f, 0.f, 0.f};
#pragma unroll
    for (int i = 0; i < 4; i++)
#pragma unroll
        for (int j = 0; j < 4; j++) acc[i][j] = zero;

#pragma unroll
    for (int ktp = 0; ktp < NKTP_E; ++ktp) {
        union { uint4 v; long l[2]; } ua[4], ub[4];
#pragma unroll
        for (int i = 0; i < 4; i++) ua[i].v = *(const uint4*)(pa[i] + (size_t)ktp * 1024);
#pragma unroll
        for (int j = 0; j < 4; j++) ub[j].v = *(const uint4*)(pb[j] + (size_t)ktp * 1024);
        __builtin_amdgcn_s_setprio(1);
#pragma unroll
        for (int h = 0; h < 2; h++)
#pragma unroll
            for (int i = 0; i < 4; i++)
#pragma unroll
                for (int j = 0; j < 4; j++)
                    acc[i][j] = __builtin_amdgcn_mfma_f32_16x16x32_fp8_fp8(
                        ua[i].l[h], ub[j].l[h], acc[i][j], 0, 0, 0);
        __builtin_amdgcn_s_setprio(0);
    }

    // epilogue: cube, weight by (ind^3*r2), reduce over columns, atomicAdd rows
    const float* fX = fbuf;
    const float* fD = fbuf + P_B;
    float wc[4];
#pragma unroll
    for (int j = 0; j < 4; j++) wc[j] = fD[col0 + (wave & 1) * 64 + j * 16 + c];
    float p[4][4];
#pragma unroll
    for (int i = 0; i < 4; i++)
#pragma unroll
        for (int r = 0; r < 4; r++) p[i][r] = 0.f;
#pragma unroll
    for (int i = 0; i < 4; i++)
#pragma unroll
        for (int j = 0; j < 4; j++)
#pragma unroll
            for (int r = 0; r < 4; r++) {
                const float v = acc[i][j][r];
                const float v3 = v * v * v;
                p[i][r] = fmaf(v3, wc[j], p[i][r]);
            }
#pragma unroll
    for (int i = 0; i < 4; i++)
#pragma unroll
        for (int r = 0; r < 4; r++) {
            float s = p[i][r];
            s += __shfl_xor(s, 1);
            s += __shfl_xor(s, 2);
            s += __shfl_xor(s, 4);
            s += __shfl_xor(s, 8);
            p[i][r] = s;
        }
    if (c == 0) {
#pragma unroll
        for (int i = 0; i < 4; i++)
#pragma unroll
            for (int r = 0; r < 4; r++) {
                const int rowg = row0 + (wave >> 1) * 64 + i * 16 + q * 4 + r;
                atomicAdd(&echo[rowg], p[i][r] * fX[rowg]);
            }
    }
}

// ---------------------------------------------------------------------------
// Head: logits = echo*h_w + h_b ; preds = sigmoid(logits)
// ---------------------------------------------------------------------------
__global__ void head_kernel(const float* __restrict__ echo, const float* __restrict__ hw,
                            const float* __restrict__ hb, float* __restrict__ out)
{
    const int i = blockIdx.x * 256 + threadIdx.x;
    if (i >= P_B) return;
    const float logit = fmaf(echo[i], hw[0], hb[0]);
    out[i] = logit;
    out[P_B + i] = 1.0f / (1.0f + expf(-logit));
}

extern "C" void kernel_launch(void* const* d_in, const int* in_sizes, int n_in,
                              void* d_out, int out_size, void* d_ws, size_t ws_size,
                              hipStream_t stream)
{
    const float* X  = (const float*)d_in[0];
    const float* D  = (const float*)d_in[1];
    const float* r  = (const float*)d_in[2];
    const float* gw = (const float*)d_in[3];
    const float* gb = (const float*)d_in[4];
    const float* hw = (const float*)d_in[5];
    const float* hb = (const float*)d_in[6];
    float* out = (float*)d_out;

    char* ws = (char*)d_ws;
    const size_t gwpk_bytes   = (size_t)32 * NKT_F * 64 * 8 * 2;      //    786,432
    const size_t embpk8_bytes = (size_t)1280 * NKTP_E * 64 * 16;      // 10,485,760

    unsigned short* gwpk   = (unsigned short*)ws;
    unsigned char*  embpk8 = (unsigned char*)(ws + gwpk_bytes);
    float* norm2 = (float*)(ws + gwpk_bytes + embpk8_bytes);
    float* echo = norm2 + (P_B + P_N);

    convert_pack_kernel<<<dim3(97), 256, 0, stream>>>(gw, gwpk, norm2);
    embed_pk_kernel<<<dim3(640), 256, 0, stream>>>(X, D, gwpk, gb, embpk8, norm2);
    finalize_kernel<<<dim3((P_B + P_N + 255) / 256), 256, 0, stream>>>(norm2, r);
    echo_pk_kernel<<<dim3(4096), 256, 0, stream>>>(embpk8, norm2, echo);
    head_kernel<<<dim3((P_B + 255) / 256), 256, 0, stream>>>(echo, hw, hb, out);
}